// Round 1
// baseline (3881.107 us; speedup 1.0000x reference)
//
#include <hip/hip_runtime.h>
#include <math.h>

#define EMBD 128
#define HIDD 128
#define NTAR 16
#define BSEQ 4096
#define G4   (4 * HIDD)   // 512 gate pre-activations per step

// ---------------------------------------------------------------------------
// Kernel 1: input projection (parallel over all timesteps)
// zx[t][j] = dot(emb[x[t]], w_ih[j]) + b_ih[j] + b_hh[j]
// One block per timestep t, 512 threads (one per gate row j).
// emb row is a 512B broadcast read (all threads same row); w_ih is 256 KB,
// L2-resident after first touch.
// ---------------------------------------------------------------------------
__global__ void input_proj_kernel(const int* __restrict__ x,
                                  const float* __restrict__ emb,
                                  const float* __restrict__ w_ih,
                                  const float* __restrict__ b_ih,
                                  const float* __restrict__ b_hh,
                                  float* __restrict__ zx) {
    const int t = blockIdx.x;
    const int j = threadIdx.x;            // 0..511
    const int idx = x[t];
    const float4* __restrict__ er = (const float4*)(emb + (long long)idx * EMBD);
    const float4* __restrict__ wr = (const float4*)(w_ih + j * EMBD);
    float acc = 0.f;
#pragma unroll
    for (int k = 0; k < EMBD / 4; ++k) {
        float4 e = er[k];
        float4 w = wr[k];
        acc += e.x * w.x + e.y * w.y + e.z * w.z + e.w * w.w;
    }
    zx[t * G4 + j] = acc + b_ih[j] + b_hh[j];
}

// ---------------------------------------------------------------------------
// Kernel 2: the sequential LSTM. ONE workgroup (recurrence is serial; any
// cross-CU sync would cost more than the compute). 512 threads, thread j
// owns row j of W_hh in 128 VGPRs (32 float4). Per step:
//   phase A (all 8 waves): dot(W_hh[j], h_prev) via LDS-broadcast float4
//     reads, add precomputed zx, apply this row's own nonlinearity
//     (sigmoid for i/f/o rows, tanh for g rows) -> a_sh[j].
//   phase B (threads 0..127): c = f*c + i*g; h = o*tanh(c); write h to LDS
//     + hs to global.
// zx for step t+1 is loaded at the top of step t to hide HBM latency.
// ---------------------------------------------------------------------------
__global__ __launch_bounds__(512, 2)
void lstm_seq_kernel(const float* __restrict__ zx,
                     const float* __restrict__ w_hh,
                     float* __restrict__ hs) {
    __shared__ float h_sh[HIDD];
    __shared__ float a_sh[G4];

    const int j = threadIdx.x;

    // Preload this thread's W_hh row into registers (128 VGPRs).
    float4 w[HIDD / 4];
    {
        const float4* __restrict__ wr = (const float4*)(w_hh + j * HIDD);
#pragma unroll
        for (int k = 0; k < HIDD / 4; ++k) w[k] = wr[k];
    }

    if (j < HIDD) h_sh[j] = 0.f;
    float c = 0.f;
    __syncthreads();

    const float4* h4 = (const float4*)h_sh;
    const bool is_g_row = (j >= 2 * HIDD) && (j < 3 * HIDD);

    float zin = zx[j];  // t = 0
    for (int t = 0; t < BSEQ; ++t) {
        // Prefetch next step's input projection (independent of this step).
        float zin_next = 0.f;
        if (t + 1 < BSEQ) zin_next = zx[(t + 1) * G4 + j];

        // dot(W_hh row j, h_prev) — h read as LDS broadcast float4s.
        float dot = 0.f;
#pragma unroll
        for (int k = 0; k < HIDD / 4; ++k) {
            float4 h = h4[k];
            dot += h.x * w[k].x + h.y * w[k].y + h.z * w[k].z + h.w * w[k].w;
        }
        const float z = zin + dot;

        // Row-local nonlinearity, spread across all 8 waves.
        float a;
        if (is_g_row) a = tanhf(z);
        else          a = 1.f / (1.f + expf(-z));
        a_sh[j] = a;
        __syncthreads();

        if (j < HIDD) {
            const float gi = a_sh[j];
            const float gf = a_sh[j + HIDD];
            const float gg = a_sh[j + 2 * HIDD];
            const float go = a_sh[j + 3 * HIDD];
            c = gf * c + gi * gg;
            const float h = go * tanhf(c);
            h_sh[j] = h;
            hs[t * HIDD + j] = h;   // fire-and-forget store
        }
        __syncthreads();

        zin = zin_next;
    }
}

// ---------------------------------------------------------------------------
// Kernel 3: final FC. out[t][n] = dot(hs[t], w_fc[n]) + b_fc[n].
// One thread per output element (65536 total). w_fc (8 KB) is L1-resident.
// ---------------------------------------------------------------------------
__global__ void fc_kernel(const float* __restrict__ hs,
                          const float* __restrict__ w_fc,
                          const float* __restrict__ b_fc,
                          float* __restrict__ out) {
    const int gid = blockIdx.x * blockDim.x + threadIdx.x;
    if (gid >= BSEQ * NTAR) return;
    const int n = gid & (NTAR - 1);
    const int t = gid >> 4;
    const float4* __restrict__ hr = (const float4*)(hs + t * HIDD);
    const float4* __restrict__ wr = (const float4*)(w_fc + n * HIDD);
    float acc = 0.f;
#pragma unroll
    for (int k = 0; k < HIDD / 4; ++k) {
        float4 h = hr[k];
        float w = 0.f;  (void)w;
        float4 wv = wr[k];
        acc += h.x * wv.x + h.y * wv.y + h.z * wv.z + h.w * wv.w;
    }
    out[gid] = acc + b_fc[n];
}

// ---------------------------------------------------------------------------
extern "C" void kernel_launch(void* const* d_in, const int* in_sizes, int n_in,
                              void* d_out, int out_size, void* d_ws, size_t ws_size,
                              hipStream_t stream) {
    const int*   x    = (const int*)d_in[0];
    const float* emb  = (const float*)d_in[1];
    const float* w_ih = (const float*)d_in[2];
    const float* w_hh = (const float*)d_in[3];
    const float* b_ih = (const float*)d_in[4];
    const float* b_hh = (const float*)d_in[5];
    const float* w_fc = (const float*)d_in[6];
    const float* b_fc = (const float*)d_in[7];
    float* out = (float*)d_out;

    // Workspace layout: zx (4096*512 f32 = 8 MB) | hs (4096*128 f32 = 2 MB)
    float* zx = (float*)d_ws;
    float* hs = zx + (size_t)BSEQ * G4;

    input_proj_kernel<<<BSEQ, G4, 0, stream>>>(x, emb, w_ih, b_ih, b_hh, zx);
    lstm_seq_kernel<<<1, G4, 0, stream>>>(zx, w_hh, hs);
    fc_kernel<<<(BSEQ * NTAR + 255) / 256, 256, 0, stream>>>(hs, w_fc, b_fc, out);
}